// Round 1
// 1202.472 us; speedup vs baseline: 1.3070x; 1.3070x over previous
//
#include <hip/hip_runtime.h>
#include <stdint.h>

#define OUT_F 11008
#define IN_F  4096
#define M_TOK 8192   // 4 * 2048

typedef __attribute__((ext_vector_type(8))) __bf16 bf16x8;
typedef __attribute__((ext_vector_type(4))) float  f32x4;

__device__ __forceinline__ unsigned short f2bf(float f) {
    // round-to-nearest-even bf16 (inputs are finite)
    uint32_t u = __float_as_uint(f);
    u += 0x7FFFu + ((u >> 16) & 1u);
    return (unsigned short)(u >> 16);
}

// -------- dequant (unchanged) --------
__global__ __launch_bounds__(256) void dequant_w(
    const int*   __restrict__ packed,
    const float* __restrict__ wrange,
    const float* __restrict__ wmin,
    unsigned short* __restrict__ wb) {
    int idx = blockIdx.x * 256 + threadIdx.x;
    const uint4* src = (const uint4*)(packed + (size_t)idx * 8);
    uint4 p0 = src[0];
    uint4 p1 = src[1];
    int g = idx >> 5;
    float r  = wrange[g] * (1.0f / 15.0f);
    float mn = wmin[g];
    uint32_t by[8] = {p0.x, p0.y, p0.z, p0.w, p1.x, p1.y, p1.z, p1.w};
    union { unsigned short s[16]; uint4 v[2]; } o;
    #pragma unroll
    for (int b = 0; b < 8; ++b) {
        uint32_t v = by[b] & 0xFFu;
        o.s[2 * b]     = f2bf((float)(v & 15u) * r + mn);
        o.s[2 * b + 1] = f2bf((float)(v >> 4)  * r + mn);
    }
    uint4* dst = (uint4*)(wb + (size_t)idx * 16);
    dst[0] = o.v[0];
    dst[1] = o.v[1];
}

// -------- cast x fp32 -> bf16 (unchanged) --------
__global__ __launch_bounds__(256) void cvt_x(const float* __restrict__ x,
                                             unsigned short* __restrict__ xb) {
    size_t i = ((size_t)blockIdx.x * 256 + threadIdx.x) * 8;
    float4 a = *(const float4*)(x + i);
    float4 b = *(const float4*)(x + i + 4);
    union { unsigned short s[8]; uint4 v; } o;
    o.s[0] = f2bf(a.x); o.s[1] = f2bf(a.y); o.s[2] = f2bf(a.z); o.s[3] = f2bf(a.w);
    o.s[4] = f2bf(b.x); o.s[5] = f2bf(b.y); o.s[6] = f2bf(b.z); o.s[7] = f2bf(b.w);
    *(uint4*)(xb + i) = o.v;
}

// -------- async global->LDS, 16 B per lane --------
__device__ __forceinline__ void async16(const void* g, void* l) {
    __builtin_amdgcn_global_load_lds(
        (__attribute__((address_space(1))) unsigned int*)g,
        (__attribute__((address_space(3))) unsigned int*)l,
        16, 0, 0);
}

// =====================================================================
// 256x256 8-phase bf16 GEMM (B^T input): C[M,N] = A[M,K] * B[N,K]^T
// 512 thr = 8 waves (2M x 4N); per-wave 128x64 out = acc[8][4] f32x4.
// LDS 128 KiB: 2 K-tile double buffer, [256][64] bf16 per matrix.
// XOR swizzle (slot ^= row&7 in 16B units) on BOTH stage-source and
// ds_read (global_load_lds dest stays linear).
// Per phase: {ds_read frags | stage 1 half-tile | bar | lgkmcnt(0) |
//             setprio(1) 16xMFMA setprio(0) | [vmcnt(4) @ph4,8] | bar}
// =====================================================================
#define BM 256
#define BN 256
#define BK 64
#define NITER 32   // K / (2*BK) = 4096/128

__global__ __launch_bounds__(512, 2) void gemm_bt(
    const unsigned short* __restrict__ A,   // [M,K] bf16 bits
    const unsigned short* __restrict__ B,   // [N,K] bf16 bits
    float* __restrict__ C,                  // [M,N] fp32
    int M, int N, int K) {
    __shared__ alignas(16) unsigned short As[2][BM * BK];  // 64 KiB
    __shared__ alignas(16) unsigned short Bs[2][BN * BK];  // 64 KiB

    const int tid  = threadIdx.x;
    const int lane = tid & 63;
    const int wid  = tid >> 6;
    const int wm   = wid >> 2;       // 0..1
    const int wn   = wid & 3;        // 0..3
    const int frow = lane & 15;
    const int quad = lane >> 4;

    // XCD-aware swizzle (gridDim.x = 1376, divisible by 8 -> bijective)
    const int cpx = gridDim.x >> 3;
    const int L   = ((int)blockIdx.x & 7) * cpx + ((int)blockIdx.x >> 3);
    const int ntn = N / BN;          // 43
    const int by  = L / ntn;
    const int bx  = L % ntn;
    const int m0  = by * BM;
    const int n0  = bx * BN;

    // ---- staging geometry: half-tile = 128 rows x 64 cols = 1024 x 16B ----
    // thread covers chunks {tid, 512+tid}; LDS dest linear, global source
    // slot pre-swizzled so that (read-swizzle o write) = identity.
    const int slr = tid >> 3;                 // local row 0..63 (h adds 64)
    const int ssl = (tid & 7) ^ (slr & 7);    // swizzled source slot

    auto stage = [&](const unsigned short* __restrict__ G, int row_base, int k0,
                     unsigned short* lds) {
        #pragma unroll
        for (int h = 0; h < 2; ++h) {
            const unsigned short* src =
                G + (size_t)(row_base + slr + h * 64) * K + k0 + ssl * 8;
            async16(src, lds + (tid + h * 512) * 8);
        }
    };

    // fragment reads: logical slot = ks*4+quad, phys = slot ^ (row&7);
    // row&7 == frow&7 for all fragment rows (row offsets are mult. of 16)
    const int fxor = frow & 7;
    auto ldA = [&](const unsigned short* buf, int r, int ks) -> bf16x8 {
        int row  = wm * 128 + r * 16 + frow;
        int slot = ((ks << 2) | quad) ^ fxor;
        return *(const bf16x8*)(buf + row * 64 + slot * 8);
    };
    auto ldB = [&](const unsigned short* buf, int c, int ks) -> bf16x8 {
        int row  = wn * 64 + c * 16 + frow;
        int slot = ((ks << 2) | quad) ^ fxor;
        return *(const bf16x8*)(buf + row * 64 + slot * 8);
    };

    f32x4 acc[8][4];
    #pragma unroll
    for (int r = 0; r < 8; ++r)
        #pragma unroll
        for (int c = 0; c < 4; ++c)
            acc[r][c] = (f32x4){0.f, 0.f, 0.f, 0.f};

    bf16x8 bfr[4][2];   // B fragments, persist across the 4 phases of a tile

    // ---- prologue: tile0 (4 halves) + B of tile1 (2 halves) in flight ----
    stage(B, n0,       0,  &Bs[0][0]);
    stage(B, n0 + 128, 0,  &Bs[0][128 * 64]);
    stage(A, m0,       0,  &As[0][0]);
    stage(A, m0 + 128, 0,  &As[0][128 * 64]);
    stage(B, n0,       BK, &Bs[1][0]);
    stage(B, n0 + 128, BK, &Bs[1][128 * 64]);
    asm volatile("s_waitcnt vmcnt(4)" ::: "memory");   // tile0 landed; B(1) in flight
    __builtin_amdgcn_s_barrier();

    for (int it = 0; it < NITER; ++it) {
        const int kA1 = (2 * it + 1) * BK;   // odd tile (buf1) A stage
        const int kT2 = (2 * it + 2) * BK;   // next even tile (buf0)
        const int kT3 = (2 * it + 3) * BK;   // next odd tile (buf1)
        const bool stg = (it < NITER - 1);

        // ======== phases 1-4: compute buf0 (tile 2it) ========
        #pragma unroll
        for (int q = 0; q < 4; ++q) {
            bf16x8 af[2][2];
            #pragma unroll
            for (int i = 0; i < 2; ++i)
                #pragma unroll
                for (int ks = 0; ks < 2; ++ks)
                    af[i][ks] = ldA(&As[0][0], 2 * q + i, ks);
            if (q == 0) {
                #pragma unroll
                for (int c = 0; c < 4; ++c)
                    #pragma unroll
                    for (int ks = 0; ks < 2; ++ks)
                        bfr[c][ks] = ldB(&Bs[0][0], c, ks);
            }
            // stage schedule: A(2it+1)@ph1-2 (buf1 A free since prev ph8),
            //                 B(2it+2)@ph3-4 (buf0 B free since ph1)
            if (q == 0)        stage(A, m0,       kA1, &As[1][0]);
            if (q == 1)        stage(A, m0 + 128, kA1, &As[1][128 * 64]);
            if (q == 2 && stg) stage(B, n0,       kT2, &Bs[0][0]);
            if (q == 3 && stg) stage(B, n0 + 128, kT2, &Bs[0][128 * 64]);

            __builtin_amdgcn_sched_barrier(0);
            __builtin_amdgcn_s_barrier();
            asm volatile("s_waitcnt lgkmcnt(0)" ::: "memory");
            __builtin_amdgcn_sched_barrier(0);
            __builtin_amdgcn_s_setprio(1);
            #pragma unroll
            for (int ks = 0; ks < 2; ++ks)
                #pragma unroll
                for (int i = 0; i < 2; ++i)
                    #pragma unroll
                    for (int c = 0; c < 4; ++c)
                        acc[2 * q + i][c] = __builtin_amdgcn_mfma_f32_16x16x32_bf16(
                            af[i][ks], bfr[c][ks], acc[2 * q + i][c], 0, 0, 0);
            __builtin_amdgcn_s_setprio(0);
            if (q == 3) {
                // tile 2it+1 (buf1) must be complete before phases 5-8 read it
                if (stg) asm volatile("s_waitcnt vmcnt(4)" ::: "memory");
                else     asm volatile("s_waitcnt vmcnt(0)" ::: "memory");
            }
            __builtin_amdgcn_sched_barrier(0);
            __builtin_amdgcn_s_barrier();
        }

        // ======== phases 5-8: compute buf1 (tile 2it+1) ========
        #pragma unroll
        for (int q = 0; q < 4; ++q) {
            bf16x8 af[2][2];
            #pragma unroll
            for (int i = 0; i < 2; ++i)
                #pragma unroll
                for (int ks = 0; ks < 2; ++ks)
                    af[i][ks] = ldA(&As[1][0], 2 * q + i, ks);
            if (q == 0) {
                #pragma unroll
                for (int c = 0; c < 4; ++c)
                    #pragma unroll
                    for (int ks = 0; ks < 2; ++ks)
                        bfr[c][ks] = ldB(&Bs[1][0], c, ks);
            }
            // stage schedule: A(2it+2)@ph5-6 (buf0 A free since ph4),
            //                 B(2it+3)@ph7-8 (buf1 B free since ph5)
            if (q == 0 && stg) stage(A, m0,       kT2, &As[0][0]);
            if (q == 1 && stg) stage(A, m0 + 128, kT2, &As[0][128 * 64]);
            if (q == 2 && stg) stage(B, n0,       kT3, &Bs[1][0]);
            if (q == 3 && stg) stage(B, n0 + 128, kT3, &Bs[1][128 * 64]);

            __builtin_amdgcn_sched_barrier(0);
            __builtin_amdgcn_s_barrier();
            asm volatile("s_waitcnt lgkmcnt(0)" ::: "memory");
            __builtin_amdgcn_sched_barrier(0);
            __builtin_amdgcn_s_setprio(1);
            #pragma unroll
            for (int ks = 0; ks < 2; ++ks)
                #pragma unroll
                for (int i = 0; i < 2; ++i)
                    #pragma unroll
                    for (int c = 0; c < 4; ++c)
                        acc[2 * q + i][c] = __builtin_amdgcn_mfma_f32_16x16x32_bf16(
                            af[i][ks], bfr[c][ks], acc[2 * q + i][c], 0, 0, 0);
            __builtin_amdgcn_s_setprio(0);
            if (q == 3 && stg) {
                // tile 2it+2 (buf0) must be complete before next iter ph1
                asm volatile("s_waitcnt vmcnt(4)" ::: "memory");
            }
            __builtin_amdgcn_sched_barrier(0);
            __builtin_amdgcn_s_barrier();
        }
    }

    // ---- epilogue: C/D layout col = lane&15, row = quad*4 + reg ----
    #pragma unroll
    for (int c = 0; c < 4; ++c) {
        int n = n0 + wn * 64 + c * 16 + frow;
        #pragma unroll
        for (int r = 0; r < 8; ++r) {
            int m = m0 + wm * 128 + r * 16 + quad * 4;
            #pragma unroll
            for (int v = 0; v < 4; ++v)
                C[(size_t)(m + v) * N + n] = acc[r][c][v];
        }
    }
}

extern "C" void kernel_launch(void* const* d_in, const int* in_sizes, int n_in,
                              void* d_out, int out_size, void* d_ws, size_t ws_size,
                              hipStream_t stream) {
    const float* x      = (const float*)d_in[0];
    const int*   packed = (const int*)d_in[1];     // uint8 promoted to int32
    const float* wr     = (const float*)d_in[2];   // f16 upcast to f32
    const float* wmn    = (const float*)d_in[3];   // f16 upcast to f32
    float* out = (float*)d_out;

    // workspace: xb [8192*4096] bf16 (64 MiB), wb [11008*4096] bf16 (86 MiB)
    unsigned short* xb = (unsigned short*)d_ws;
    unsigned short* wb = (unsigned short*)((char*)d_ws + (size_t)M_TOK * IN_F * 2);

    cvt_x<<<(M_TOK * IN_F) / (256 * 8), 256, 0, stream>>>(x, xb);
    dequant_w<<<(OUT_F * IN_F / 2) / (256 * 8), 256, 0, stream>>>(packed, wr, wmn, wb);

    // 32 x 43 = 1376 blocks (divisible by 8 -> XCD swizzle bijective)
    dim3 grid((M_TOK / BM) * (OUT_F / BN));
    gemm_bt<<<grid, 512, 0, stream>>>(xb, wb, out, M_TOK, OUT_F, IN_F);
}